// Round 1
// baseline (1718.680 us; speedup 1.0000x reference)
//
#include <hip/hip_runtime.h>
#include <hip/hip_bf16.h>
#include <math.h>

#define BN_EPS 1e-5f

// ================= CSR build =================
__global__ void hist_kernel(const int* __restrict__ row, int* __restrict__ cnt, int nE) {
    int i = blockIdx.x * blockDim.x + threadIdx.x;
    if (i < nE) atomicAdd(&cnt[row[i]], 1);
}

__global__ void scanA_kernel(const int* __restrict__ cnt, int* __restrict__ part,
                             int* __restrict__ blkSums, int n) {
    __shared__ int sm[256];
    int t = threadIdx.x;
    int base = blockIdx.x * 1024 + t * 4;
    int c0 = (base + 0 < n) ? cnt[base + 0] : 0;
    int c1 = (base + 1 < n) ? cnt[base + 1] : 0;
    int c2 = (base + 2 < n) ? cnt[base + 2] : 0;
    int c3 = (base + 3 < n) ? cnt[base + 3] : 0;
    int s = c0 + c1 + c2 + c3;
    sm[t] = s;
    __syncthreads();
    for (int d = 1; d < 256; d <<= 1) {
        int v = (t >= d) ? sm[t - d] : 0;
        __syncthreads();
        sm[t] += v;
        __syncthreads();
    }
    int excl = sm[t] - s;
    if (t == 255) blkSums[blockIdx.x] = sm[255];
    int p = excl;
    if (base + 0 < n) part[base + 0] = p; p += c0;
    if (base + 1 < n) part[base + 1] = p; p += c1;
    if (base + 2 < n) part[base + 2] = p; p += c2;
    if (base + 3 < n) part[base + 3] = p;
}

__global__ void scanB_kernel(const int* __restrict__ blkSums, int* __restrict__ blkOffs, int nb) {
    __shared__ int sm[128];
    int t = threadIdx.x;
    int s = (t < nb) ? blkSums[t] : 0;
    sm[t] = s;
    __syncthreads();
    for (int d = 1; d < 128; d <<= 1) {
        int v = (t >= d) ? sm[t - d] : 0;
        __syncthreads();
        sm[t] += v;
        __syncthreads();
    }
    if (t < nb) blkOffs[t] = sm[t] - s;
}

__global__ void scanC_kernel(int* __restrict__ offsets, int* __restrict__ cursor,
                             const int* __restrict__ blkOffs, const int* __restrict__ blkSums,
                             int n, int nb) {
    int i = blockIdx.x * blockDim.x + threadIdx.x;
    if (i < n) {
        int off = offsets[i] + blkOffs[i >> 10];
        offsets[i] = off;
        cursor[i] = off;
    }
    if (i == 0) offsets[n] = blkOffs[nb - 1] + blkSums[nb - 1];
}

__global__ void scatter_kernel(const int* __restrict__ row, const int* __restrict__ col,
                               const float* __restrict__ val, int* __restrict__ cursor,
                               int* __restrict__ col_s, float* __restrict__ val_s, int nE) {
    int i = blockIdx.x * blockDim.x + threadIdx.x;
    if (i < nE) {
        int r = row[i];
        int p = atomicAdd(&cursor[r], 1);
        col_s[p] = col[i];
        val_s[p] = val[i];
    }
}

// ================= weight prep =================
__global__ void fold_bn_kernel(const float* __restrict__ W, const float* __restrict__ b,
                               const float* __restrict__ gamma, const float* __restrict__ beta,
                               const float* __restrict__ mean, const float* __restrict__ var,
                               float* __restrict__ Wf, float* __restrict__ bf, int K, int N) {
    int i = blockIdx.x * blockDim.x + threadIdx.x;
    if (i < K * N) {
        int nn = i % N;
        float sc = gamma[nn] * rsqrtf(var[nn] + BN_EPS);
        Wf[i] = W[i] * sc;
    }
    if (i < N) {
        float sc = gamma[i] * rsqrtf(var[i] + BN_EPS);
        bf[i] = (b[i] - mean[i]) * sc + beta[i];
    }
}

__global__ void pad_w3_kernel(const float* __restrict__ W3, float* __restrict__ W3p, int K) {
    int i = blockIdx.x * blockDim.x + threadIdx.x;  // over K*64
    if (i < K * 64) {
        int k = i >> 6, nn = i & 63;
        W3p[i] = (nn < 40) ? W3[k * 40 + nn] : 0.0f;
    }
}

// ================= SpMM (wave per row, CSR) =================
template <int F>
__global__ void spmm_kernel(const int* __restrict__ offsets, const int* __restrict__ col_s,
                            const float* __restrict__ val_s, const float* __restrict__ x,
                            float* __restrict__ out, int nRows) {
    constexpr int VW = F / 64;
    int wave = threadIdx.x >> 6;
    int lane = threadIdx.x & 63;
    int r = blockIdx.x * 4 + wave;
    if (r >= nRows) return;
    int start = offsets[r], end = offsets[r + 1];
    if constexpr (VW == 4) {
        float4 a = make_float4(0.f, 0.f, 0.f, 0.f);
        for (int j = start; j < end; ++j) {
            int c = col_s[j];
            float v = val_s[j];
            const float4 xv = *reinterpret_cast<const float4*>(x + (size_t)c * F + lane * 4);
            a.x += v * xv.x; a.y += v * xv.y; a.z += v * xv.z; a.w += v * xv.w;
        }
        *reinterpret_cast<float4*>(out + (size_t)r * F + lane * 4) = a;
    } else if constexpr (VW == 2) {
        float2 a = make_float2(0.f, 0.f);
        for (int j = start; j < end; ++j) {
            int c = col_s[j];
            float v = val_s[j];
            const float2 xv = *reinterpret_cast<const float2*>(x + (size_t)c * F + lane * 2);
            a.x += v * xv.x; a.y += v * xv.y;
        }
        *reinterpret_cast<float2*>(out + (size_t)r * F + lane * 2) = a;
    } else {
        float a = 0.f;
        for (int j = start; j < end; ++j) {
            int c = col_s[j];
            float v = val_s[j];
            a += v * x[(size_t)c * F + lane];
        }
        out[(size_t)r * F + lane] = a;
    }
}

// SpMM over padded-64 y, + bias + log_softmax over first 40 lanes
__global__ void spmm3_lsm_kernel(const int* __restrict__ offsets, const int* __restrict__ col_s,
                                 const float* __restrict__ val_s, const float* __restrict__ y,
                                 const float* __restrict__ b3, float* __restrict__ out, int nRows) {
    int wave = threadIdx.x >> 6;
    int lane = threadIdx.x & 63;
    int r = blockIdx.x * 4 + wave;
    if (r >= nRows) return;
    int start = offsets[r], end = offsets[r + 1];
    float acc = 0.f;
    for (int j = start; j < end; ++j) {
        int c = col_s[j];
        float v = val_s[j];
        acc += v * y[(size_t)c * 64 + lane];
    }
    float val = (lane < 40) ? (acc + b3[lane]) : -INFINITY;
    float m = val;
    for (int s = 32; s >= 1; s >>= 1) m = fmaxf(m, __shfl_xor(m, s));
    float e = (lane < 40) ? expf(val - m) : 0.f;
    float sum = e;
    for (int s = 32; s >= 1; s >>= 1) sum += __shfl_xor(sum, s);
    if (lane < 40) out[(size_t)r * 40 + lane] = val - m - logf(sum);
}

// ================= fp32 GEMM, 64x64 tile, 4x4 per thread =================
template <int K, int N, bool RELU, bool HASBIAS>
__global__ __launch_bounds__(256) void gemm_kernel(const float* __restrict__ A,
                                                   const float* __restrict__ W,
                                                   const float* __restrict__ bias,
                                                   float* __restrict__ C, int M) {
    __shared__ float As[16][68];
    __shared__ float Bs[16][68];
    int tid = threadIdx.x;
    int tx = tid & 15, ty = tid >> 4;
    int m0 = blockIdx.x * 64;
    int n0 = blockIdx.y * 64;
    float acc[4][4] = {};
    int arow = tid >> 2;  // 0..63
    int akq = tid & 3;    // 0..3
    int brow = tid >> 4;  // 0..15
    int bnq = tid & 15;   // 0..15
    const float* Aload = A + (size_t)(m0 + arow) * K + akq * 4;
    const float* Wload = W + (size_t)brow * N + n0 + bnq * 4;
    for (int k0 = 0; k0 < K; k0 += 16) {
        float4 av = *reinterpret_cast<const float4*>(Aload + k0);
        float4 bv = *reinterpret_cast<const float4*>(Wload + (size_t)k0 * N);
        __syncthreads();
        As[akq * 4 + 0][arow] = av.x;
        As[akq * 4 + 1][arow] = av.y;
        As[akq * 4 + 2][arow] = av.z;
        As[akq * 4 + 3][arow] = av.w;
        *reinterpret_cast<float4*>(&Bs[brow][bnq * 4]) = bv;
        __syncthreads();
#pragma unroll
        for (int k = 0; k < 16; ++k) {
            float4 a = *reinterpret_cast<const float4*>(&As[k][ty * 4]);
            float4 b = *reinterpret_cast<const float4*>(&Bs[k][tx * 4]);
            float a4[4] = {a.x, a.y, a.z, a.w};
            float b4[4] = {b.x, b.y, b.z, b.w};
#pragma unroll
            for (int i = 0; i < 4; ++i)
#pragma unroll
                for (int j = 0; j < 4; ++j) acc[i][j] += a4[i] * b4[j];
        }
    }
    float bb[4] = {0.f, 0.f, 0.f, 0.f};
    if (HASBIAS) {
        float4 bv = *reinterpret_cast<const float4*>(&bias[n0 + tx * 4]);
        bb[0] = bv.x; bb[1] = bv.y; bb[2] = bv.z; bb[3] = bv.w;
    }
#pragma unroll
    for (int i = 0; i < 4; ++i) {
        int r = m0 + ty * 4 + i;
        if (r < M) {
            float4 o;
            float v0 = acc[i][0] + bb[0];
            float v1 = acc[i][1] + bb[1];
            float v2 = acc[i][2] + bb[2];
            float v3 = acc[i][3] + bb[3];
            if (RELU) {
                v0 = fmaxf(v0, 0.f); v1 = fmaxf(v1, 0.f);
                v2 = fmaxf(v2, 0.f); v3 = fmaxf(v3, 0.f);
            }
            o.x = v0; o.y = v1; o.z = v2; o.w = v3;
            *reinterpret_cast<float4*>(&C[(size_t)r * N + n0 + tx * 4]) = o;
        }
    }
}

// ================= launch =================
extern "C" void kernel_launch(void* const* d_in, const int* in_sizes, int n_in,
                              void* d_out, int out_size, void* d_ws, size_t ws_size,
                              hipStream_t stream) {
    const float* x = (const float*)d_in[0];
    const int* erow = (const int*)d_in[1];
    const int* ecol = (const int*)d_in[2];
    const float* evals = (const float*)d_in[3];
    const float* W1 = (const float*)d_in[4];
    const float* b1 = (const float*)d_in[5];
    const float* W2 = (const float*)d_in[6];
    const float* b2 = (const float*)d_in[7];
    const float* W3 = (const float*)d_in[8];
    const float* b3 = (const float*)d_in[9];
    const float* gamma1 = (const float*)d_in[10];
    const float* beta1 = (const float*)d_in[11];
    const float* mean1 = (const float*)d_in[12];
    const float* var1 = (const float*)d_in[13];
    const float* gamma2 = (const float*)d_in[14];
    const float* beta2 = (const float*)d_in[15];
    const float* mean2 = (const float*)d_in[16];
    const float* var2 = (const float*)d_in[17];
    float* out = (float*)d_out;

    int nodes = in_sizes[0] / 128;
    int nE = in_sizes[1];
    int padRows = (nodes + 63) & ~63;

    char* p = (char*)d_ws;
    auto carve = [&](size_t bytes) {
        void* r = (void*)p;
        p += (bytes + 255) & ~(size_t)255;
        return r;
    };
    int* offsets = (int*)carve((size_t)(nodes + 1) * 4);
    int* cursor = (int*)carve((size_t)(nodes + 1) * 4);
    int* blkSums = (int*)carve(1024);
    int* blkOffs = (int*)carve(1024);
    int* col_s = (int*)carve((size_t)nE * 4);
    float* val_s = (float*)carve((size_t)nE * 4);
    float* W1f = (float*)carve(128 * 256 * 4);
    float* b1f = (float*)carve(256 * 4);
    float* W2f = (float*)carve(256 * 256 * 4);
    float* b2f = (float*)carve(256 * 4);
    float* W3p = (float*)carve(256 * 64 * 4);
    float* bufA = (float*)carve((size_t)padRows * 256 * 4);
    float* bufB = (float*)carve((size_t)padRows * 256 * 4);

    // ---- CSR build ----
    hipMemsetAsync(cursor, 0, (size_t)(nodes + 1) * 4, stream);
    int gE = (nE + 255) / 256;
    hist_kernel<<<gE, 256, 0, stream>>>(erow, cursor, nE);
    int nb = (nodes + 1023) / 1024;
    scanA_kernel<<<nb, 256, 0, stream>>>(cursor, offsets, blkSums, nodes);
    scanB_kernel<<<1, 128, 0, stream>>>(blkSums, blkOffs, nb);
    scanC_kernel<<<(nodes + 255) / 256, 256, 0, stream>>>(offsets, cursor, blkOffs, blkSums, nodes, nb);
    scatter_kernel<<<gE, 256, 0, stream>>>(erow, ecol, evals, cursor, col_s, val_s, nE);

    // ---- weight prep ----
    fold_bn_kernel<<<(128 * 256 + 255) / 256, 256, 0, stream>>>(W1, b1, gamma1, beta1, mean1, var1,
                                                                W1f, b1f, 128, 256);
    fold_bn_kernel<<<(256 * 256 + 255) / 256, 256, 0, stream>>>(W2, b2, gamma2, beta2, mean2, var2,
                                                                W2f, b2f, 256, 256);
    pad_w3_kernel<<<(256 * 64 + 255) / 256, 256, 0, stream>>>(W3, W3p, 256);

    // ---- pipeline ----
    int gR = (nodes + 3) / 4;
    dim3 gemm_g(padRows / 64, 4);
    dim3 gemm_g3(padRows / 64, 1);

    // layer 1: h = A*x ; z1 = relu(h @ W1' + b1')
    spmm_kernel<128><<<gR, 256, 0, stream>>>(offsets, col_s, val_s, x, bufA, nodes);
    gemm_kernel<128, 256, true, true><<<gemm_g, 256, 0, stream>>>(bufA, W1f, b1f, bufB, nodes);
    // layer 2: h2 = A*z1 ; z2 = relu(h2 @ W2' + b2')
    spmm_kernel<256><<<gR, 256, 0, stream>>>(offsets, col_s, val_s, bufB, bufA, nodes);
    gemm_kernel<256, 256, true, true><<<gemm_g, 256, 0, stream>>>(bufA, W2f, b2f, bufB, nodes);
    // layer 3 (reassociated): y = z2 @ W3 (padded to 64 cols); out = logsoftmax(A*y + b3)
    gemm_kernel<256, 64, false, false><<<gemm_g3, 256, 0, stream>>>(bufB, W3p, nullptr, bufA, nodes);
    spmm3_lsm_kernel<<<gR, 256, 0, stream>>>(offsets, col_s, val_s, bufA, b3, out, nodes);
}

// Round 2
// 1471.801 us; speedup vs baseline: 1.1677x; 1.1677x over previous
//
#include <hip/hip_runtime.h>
#include <hip/hip_bf16.h>
#include <math.h>

#define BN_EPS 1e-5f

typedef float f32x4 __attribute__((ext_vector_type(4)));
typedef float f32x2 __attribute__((ext_vector_type(2)));

// ================= CSR build =================
__global__ void hist_kernel(const int* __restrict__ row, int* __restrict__ cnt, int nE) {
    int i = blockIdx.x * blockDim.x + threadIdx.x;
    if (i < nE) atomicAdd(&cnt[row[i]], 1);
}

__global__ void scanA_kernel(const int* __restrict__ cnt, int* __restrict__ part,
                             int* __restrict__ blkSums, int n) {
    __shared__ int sm[256];
    int t = threadIdx.x;
    int base = blockIdx.x * 1024 + t * 4;
    int c0 = (base + 0 < n) ? cnt[base + 0] : 0;
    int c1 = (base + 1 < n) ? cnt[base + 1] : 0;
    int c2 = (base + 2 < n) ? cnt[base + 2] : 0;
    int c3 = (base + 3 < n) ? cnt[base + 3] : 0;
    int s = c0 + c1 + c2 + c3;
    sm[t] = s;
    __syncthreads();
    for (int d = 1; d < 256; d <<= 1) {
        int v = (t >= d) ? sm[t - d] : 0;
        __syncthreads();
        sm[t] += v;
        __syncthreads();
    }
    int excl = sm[t] - s;
    if (t == 255) blkSums[blockIdx.x] = sm[255];
    int p = excl;
    if (base + 0 < n) part[base + 0] = p; p += c0;
    if (base + 1 < n) part[base + 1] = p; p += c1;
    if (base + 2 < n) part[base + 2] = p; p += c2;
    if (base + 3 < n) part[base + 3] = p;
}

__global__ void scanB_kernel(const int* __restrict__ blkSums, int* __restrict__ blkOffs, int nb) {
    __shared__ int sm[128];
    int t = threadIdx.x;
    int s = (t < nb) ? blkSums[t] : 0;
    sm[t] = s;
    __syncthreads();
    for (int d = 1; d < 128; d <<= 1) {
        int v = (t >= d) ? sm[t - d] : 0;
        __syncthreads();
        sm[t] += v;
        __syncthreads();
    }
    if (t < nb) blkOffs[t] = sm[t] - s;
}

__global__ void scanC_kernel(int* __restrict__ offsets, int* __restrict__ cursor,
                             const int* __restrict__ blkOffs, const int* __restrict__ blkSums,
                             int n, int nb) {
    int i = blockIdx.x * blockDim.x + threadIdx.x;
    if (i < n) {
        int off = offsets[i] + blkOffs[i >> 10];
        offsets[i] = off;
        cursor[i] = off;
    }
    if (i == 0) offsets[n] = blkOffs[nb - 1] + blkSums[nb - 1];
}

__global__ void scatter_kernel(const int* __restrict__ row, const int* __restrict__ col,
                               const float* __restrict__ val, int* __restrict__ cursor,
                               int* __restrict__ col_s, float* __restrict__ val_s, int nE) {
    int i = blockIdx.x * blockDim.x + threadIdx.x;
    if (i < nE) {
        int r = row[i];
        int p = atomicAdd(&cursor[r], 1);
        col_s[p] = col[i];
        val_s[p] = val[i];
    }
}

// ================= weight prep =================
__global__ void fold_bn_kernel(const float* __restrict__ W, const float* __restrict__ b,
                               const float* __restrict__ gamma, const float* __restrict__ beta,
                               const float* __restrict__ mean, const float* __restrict__ var,
                               float* __restrict__ Wf, float* __restrict__ bf, int K, int N) {
    int i = blockIdx.x * blockDim.x + threadIdx.x;
    if (i < K * N) {
        int nn = i % N;
        float sc = gamma[nn] * rsqrtf(var[nn] + BN_EPS);
        Wf[i] = W[i] * sc;
    }
    if (i < N) {
        float sc = gamma[i] * rsqrtf(var[i] + BN_EPS);
        bf[i] = (b[i] - mean[i]) * sc + beta[i];
    }
}

__global__ void pad_w3_kernel(const float* __restrict__ W3, float* __restrict__ W3p, int K) {
    int i = blockIdx.x * blockDim.x + threadIdx.x;  // over K*64
    if (i < K * 64) {
        int k = i >> 6, nn = i & 63;
        W3p[i] = (nn < 40) ? W3[k * 40 + nn] : 0.0f;
    }
}

// ================= SpMM (wave per row, CSR, unroll-4, NT output) =================
// Output is streamed (no reuse before eviction pressure matters) -> nontemporal
// store keeps the gather source resident in Infinity Cache.
template <int F>
__global__ void spmm_kernel(const int* __restrict__ offsets, const int* __restrict__ col_s,
                            const float* __restrict__ val_s, const float* __restrict__ x,
                            float* __restrict__ out, int nRows) {
    constexpr int VW = F / 64;
    int wave = threadIdx.x >> 6;
    int lane = threadIdx.x & 63;
    int r = blockIdx.x * 4 + wave;
    if (r >= nRows) return;
    int start = offsets[r], end = offsets[r + 1];
    if constexpr (VW == 4) {
        f32x4 a0 = {0.f, 0.f, 0.f, 0.f}, a1 = {0.f, 0.f, 0.f, 0.f};
        const float* xb = x + lane * 4;
        int j = start;
        for (; j + 3 < end; j += 4) {
            int c0 = col_s[j], c1 = col_s[j + 1], c2 = col_s[j + 2], c3 = col_s[j + 3];
            float v0 = val_s[j], v1 = val_s[j + 1], v2 = val_s[j + 2], v3 = val_s[j + 3];
            f32x4 x0 = *reinterpret_cast<const f32x4*>(xb + (size_t)c0 * F);
            f32x4 x1 = *reinterpret_cast<const f32x4*>(xb + (size_t)c1 * F);
            f32x4 x2 = *reinterpret_cast<const f32x4*>(xb + (size_t)c2 * F);
            f32x4 x3 = *reinterpret_cast<const f32x4*>(xb + (size_t)c3 * F);
            a0 += v0 * x0; a1 += v1 * x1; a0 += v2 * x2; a1 += v3 * x3;
        }
        for (; j < end; ++j) {
            int c = col_s[j];
            float v = val_s[j];
            a0 += v * *reinterpret_cast<const f32x4*>(xb + (size_t)c * F);
        }
        f32x4 res = a0 + a1;
        __builtin_nontemporal_store(res, reinterpret_cast<f32x4*>(out + (size_t)r * F + lane * 4));
    } else if constexpr (VW == 2) {
        f32x2 a0 = {0.f, 0.f}, a1 = {0.f, 0.f};
        const float* xb = x + lane * 2;
        int j = start;
        for (; j + 3 < end; j += 4) {
            int c0 = col_s[j], c1 = col_s[j + 1], c2 = col_s[j + 2], c3 = col_s[j + 3];
            float v0 = val_s[j], v1 = val_s[j + 1], v2 = val_s[j + 2], v3 = val_s[j + 3];
            f32x2 x0 = *reinterpret_cast<const f32x2*>(xb + (size_t)c0 * F);
            f32x2 x1 = *reinterpret_cast<const f32x2*>(xb + (size_t)c1 * F);
            f32x2 x2 = *reinterpret_cast<const f32x2*>(xb + (size_t)c2 * F);
            f32x2 x3 = *reinterpret_cast<const f32x2*>(xb + (size_t)c3 * F);
            a0 += v0 * x0; a1 += v1 * x1; a0 += v2 * x2; a1 += v3 * x3;
        }
        for (; j < end; ++j) {
            int c = col_s[j];
            float v = val_s[j];
            a0 += v * *reinterpret_cast<const f32x2*>(xb + (size_t)c * F);
        }
        f32x2 res = a0 + a1;
        __builtin_nontemporal_store(res, reinterpret_cast<f32x2*>(out + (size_t)r * F + lane * 2));
    }
}

// SpMM over padded-64 y, + bias + log_softmax over first 40 lanes; NT final store
__global__ void spmm3_lsm_kernel(const int* __restrict__ offsets, const int* __restrict__ col_s,
                                 const float* __restrict__ val_s, const float* __restrict__ y,
                                 const float* __restrict__ b3, float* __restrict__ out, int nRows) {
    int wave = threadIdx.x >> 6;
    int lane = threadIdx.x & 63;
    int r = blockIdx.x * 4 + wave;
    if (r >= nRows) return;
    int start = offsets[r], end = offsets[r + 1];
    float a0 = 0.f, a1 = 0.f;
    const float* yb = y + lane;
    int j = start;
    for (; j + 3 < end; j += 4) {
        int c0 = col_s[j], c1 = col_s[j + 1], c2 = col_s[j + 2], c3 = col_s[j + 3];
        float v0 = val_s[j], v1 = val_s[j + 1], v2 = val_s[j + 2], v3 = val_s[j + 3];
        a0 += v0 * yb[(size_t)c0 * 64];
        a1 += v1 * yb[(size_t)c1 * 64];
        a0 += v2 * yb[(size_t)c2 * 64];
        a1 += v3 * yb[(size_t)c3 * 64];
    }
    for (; j < end; ++j) {
        a0 += val_s[j] * yb[(size_t)col_s[j] * 64];
    }
    float acc = a0 + a1;
    float val = (lane < 40) ? (acc + b3[lane]) : -INFINITY;
    float m = val;
    for (int s = 32; s >= 1; s >>= 1) m = fmaxf(m, __shfl_xor(m, s));
    float e = (lane < 40) ? expf(val - m) : 0.f;
    float sum = e;
    for (int s = 32; s >= 1; s >>= 1) sum += __shfl_xor(sum, s);
    if (lane < 40)
        __builtin_nontemporal_store(val - m - logf(sum), out + (size_t)r * 40 + lane);
}

// ================= fp32 GEMM, 64x64 tile, 4x4 per thread =================
template <int K, int N, bool RELU, bool HASBIAS>
__global__ __launch_bounds__(256) void gemm_kernel(const float* __restrict__ A,
                                                   const float* __restrict__ W,
                                                   const float* __restrict__ bias,
                                                   float* __restrict__ C, int M) {
    __shared__ float As[16][68];
    __shared__ float Bs[16][68];
    int tid = threadIdx.x;
    int tx = tid & 15, ty = tid >> 4;
    int m0 = blockIdx.x * 64;
    int n0 = blockIdx.y * 64;
    float acc[4][4] = {};
    int arow = tid >> 2;  // 0..63
    int akq = tid & 3;    // 0..3
    int brow = tid >> 4;  // 0..15
    int bnq = tid & 15;   // 0..15
    const float* Aload = A + (size_t)(m0 + arow) * K + akq * 4;
    const float* Wload = W + (size_t)brow * N + n0 + bnq * 4;
    for (int k0 = 0; k0 < K; k0 += 16) {
        float4 av = *reinterpret_cast<const float4*>(Aload + k0);
        float4 bv = *reinterpret_cast<const float4*>(Wload + (size_t)k0 * N);
        __syncthreads();
        As[akq * 4 + 0][arow] = av.x;
        As[akq * 4 + 1][arow] = av.y;
        As[akq * 4 + 2][arow] = av.z;
        As[akq * 4 + 3][arow] = av.w;
        *reinterpret_cast<float4*>(&Bs[brow][bnq * 4]) = bv;
        __syncthreads();
#pragma unroll
        for (int k = 0; k < 16; ++k) {
            float4 a = *reinterpret_cast<const float4*>(&As[k][ty * 4]);
            float4 b = *reinterpret_cast<const float4*>(&Bs[k][tx * 4]);
            float a4[4] = {a.x, a.y, a.z, a.w};
            float b4[4] = {b.x, b.y, b.z, b.w};
#pragma unroll
            for (int i = 0; i < 4; ++i)
#pragma unroll
                for (int j = 0; j < 4; ++j) acc[i][j] += a4[i] * b4[j];
        }
    }
    float bb[4] = {0.f, 0.f, 0.f, 0.f};
    if (HASBIAS) {
        float4 bv = *reinterpret_cast<const float4*>(&bias[n0 + tx * 4]);
        bb[0] = bv.x; bb[1] = bv.y; bb[2] = bv.z; bb[3] = bv.w;
    }
#pragma unroll
    for (int i = 0; i < 4; ++i) {
        int r = m0 + ty * 4 + i;
        if (r < M) {
            float4 o;
            float v0 = acc[i][0] + bb[0];
            float v1 = acc[i][1] + bb[1];
            float v2 = acc[i][2] + bb[2];
            float v3 = acc[i][3] + bb[3];
            if (RELU) {
                v0 = fmaxf(v0, 0.f); v1 = fmaxf(v1, 0.f);
                v2 = fmaxf(v2, 0.f); v3 = fmaxf(v3, 0.f);
            }
            o.x = v0; o.y = v1; o.z = v2; o.w = v3;
            *reinterpret_cast<float4*>(&C[(size_t)r * N + n0 + tx * 4]) = o;
        }
    }
}

// ================= launch =================
extern "C" void kernel_launch(void* const* d_in, const int* in_sizes, int n_in,
                              void* d_out, int out_size, void* d_ws, size_t ws_size,
                              hipStream_t stream) {
    const float* x = (const float*)d_in[0];
    const int* erow = (const int*)d_in[1];
    const int* ecol = (const int*)d_in[2];
    const float* evals = (const float*)d_in[3];
    const float* W1 = (const float*)d_in[4];
    const float* b1 = (const float*)d_in[5];
    const float* W2 = (const float*)d_in[6];
    const float* b2 = (const float*)d_in[7];
    const float* W3 = (const float*)d_in[8];
    const float* b3 = (const float*)d_in[9];
    const float* gamma1 = (const float*)d_in[10];
    const float* beta1 = (const float*)d_in[11];
    const float* mean1 = (const float*)d_in[12];
    const float* var1 = (const float*)d_in[13];
    const float* gamma2 = (const float*)d_in[14];
    const float* beta2 = (const float*)d_in[15];
    const float* mean2 = (const float*)d_in[16];
    const float* var2 = (const float*)d_in[17];
    float* out = (float*)d_out;

    int nodes = in_sizes[0] / 128;
    int nE = in_sizes[1];
    int padRows = (nodes + 63) & ~63;

    char* p = (char*)d_ws;
    auto carve = [&](size_t bytes) {
        void* r = (void*)p;
        p += (bytes + 255) & ~(size_t)255;
        return r;
    };
    int* offsets = (int*)carve((size_t)(nodes + 1) * 4);
    int* cursor = (int*)carve((size_t)(nodes + 1) * 4);
    int* blkSums = (int*)carve(1024);
    int* blkOffs = (int*)carve(1024);
    int* col_s = (int*)carve((size_t)nE * 4);
    float* val_s = (float*)carve((size_t)nE * 4);
    float* W1f = (float*)carve(128 * 256 * 4);
    float* b1f = (float*)carve(256 * 4);
    float* W2f = (float*)carve(256 * 256 * 4);
    float* b2f = (float*)carve(256 * 4);
    float* W3p = (float*)carve(256 * 64 * 4);
    float* bufA = (float*)carve((size_t)padRows * 256 * 4);
    float* bufB = (float*)carve((size_t)padRows * 256 * 4);

    // ---- CSR build ----
    hipMemsetAsync(cursor, 0, (size_t)(nodes + 1) * 4, stream);
    int gE = (nE + 255) / 256;
    hist_kernel<<<gE, 256, 0, stream>>>(erow, cursor, nE);
    int nb = (nodes + 1023) / 1024;
    scanA_kernel<<<nb, 256, 0, stream>>>(cursor, offsets, blkSums, nodes);
    scanB_kernel<<<1, 128, 0, stream>>>(blkSums, blkOffs, nb);
    scanC_kernel<<<(nodes + 255) / 256, 256, 0, stream>>>(offsets, cursor, blkOffs, blkSums, nodes, nb);
    scatter_kernel<<<gE, 256, 0, stream>>>(erow, ecol, evals, cursor, col_s, val_s, nE);

    // ---- weight prep ----
    fold_bn_kernel<<<(128 * 256 + 255) / 256, 256, 0, stream>>>(W1, b1, gamma1, beta1, mean1, var1,
                                                                W1f, b1f, 128, 256);
    fold_bn_kernel<<<(256 * 256 + 255) / 256, 256, 0, stream>>>(W2, b2, gamma2, beta2, mean2, var2,
                                                                W2f, b2f, 256, 256);
    pad_w3_kernel<<<(256 * 64 + 255) / 256, 256, 0, stream>>>(W3, W3p, 256);

    // ---- pipeline ----
    int gR = (nodes + 3) / 4;
    dim3 gemm_g(padRows / 64, 4);
    dim3 gemm_g3(padRows / 64, 1);

    // layer 1: h = A*x ; z1 = relu(h @ W1' + b1')
    spmm_kernel<128><<<gR, 256, 0, stream>>>(offsets, col_s, val_s, x, bufA, nodes);
    gemm_kernel<128, 256, true, true><<<gemm_g, 256, 0, stream>>>(bufA, W1f, b1f, bufB, nodes);
    // layer 2: h2 = A*z1 ; z2 = relu(h2 @ W2' + b2')
    spmm_kernel<256><<<gR, 256, 0, stream>>>(offsets, col_s, val_s, bufB, bufA, nodes);
    gemm_kernel<256, 256, true, true><<<gemm_g, 256, 0, stream>>>(bufA, W2f, b2f, bufB, nodes);
    // layer 3 (reassociated): y = z2 @ W3 (padded to 64 cols); out = logsoftmax(A*y + b3)
    gemm_kernel<256, 64, false, false><<<gemm_g3, 256, 0, stream>>>(bufB, W3p, nullptr, bufA, nodes);
    spmm3_lsm_kernel<<<gR, 256, 0, stream>>>(offsets, col_s, val_s, bufA, b3, out, nodes);
}